// Round 17
// baseline (125.585 us; speedup 1.0000x reference)
//
#include <hip/hip_runtime.h>

// Problem constants
#define NB    16
#define NS    2000
#define ND    512      // input dim
#define NG    2        // groups
#define NK    320      // vars per group
#define NV    640      // G*K
#define NDCV  128      // per-group codevector dim
#define NTOK  32000    // B*S
#define TAUF  2.0f
#define EPSF  1e-7f

#define TPB      16
#define NTHREADS 640
#define TIE_THR  4.0e-3f   // covers f16-GEMM err + f16 logits storage err

using half8   = __attribute__((ext_vector_type(8))) _Float16;
using half4   = __attribute__((ext_vector_type(4))) _Float16;
using float4v = __attribute__((ext_vector_type(4))) float;

__device__ inline half8 cvt8hi(float4 p0, float4 p1) {
    half8 a;
    a[0] = (_Float16)p0.x; a[1] = (_Float16)p0.y;
    a[2] = (_Float16)p0.z; a[3] = (_Float16)p0.w;
    a[4] = (_Float16)p1.x; a[5] = (_Float16)p1.y;
    a[6] = (_Float16)p1.z; a[7] = (_Float16)p1.w;
    return a;
}

__device__ inline bool beats(float za, int ka, float zb, int kb) {
    return (za > zb) || (za == zb && ka < kb);
}

// ---- DPP 16-lane (row) rotations: VALU-pipe lane exchange. row_ror:N = 0x120|N.
template <int CTRL>
__device__ __forceinline__ float dpp_rorf(float x) {
    return __int_as_float(__builtin_amdgcn_update_dpp(
        __float_as_int(x), __float_as_int(x), CTRL, 0xF, 0xF, false));
}
template <int CTRL>
__device__ __forceinline__ int dpp_rori(int x) {
    return __builtin_amdgcn_update_dpp(x, x, CTRL, 0xF, 0xF, false);
}

__device__ __forceinline__ float qsum16(float s) {
    s += dpp_rorf<0x128>(s);
    s += dpp_rorf<0x124>(s);
    s += dpp_rorf<0x122>(s);
    s += dpp_rorf<0x121>(s);
    return s;
}

__device__ __forceinline__ void qargmax16(float& z1, int& k1) {
    {
        float oz = dpp_rorf<0x128>(z1); int ok = dpp_rori<0x128>(k1);
        if (beats(oz, ok, z1, k1)) { z1 = oz; k1 = ok; }
    }
    {
        float oz = dpp_rorf<0x124>(z1); int ok = dpp_rori<0x124>(k1);
        if (beats(oz, ok, z1, k1)) { z1 = oz; k1 = ok; }
    }
    {
        float oz = dpp_rorf<0x122>(z1); int ok = dpp_rori<0x122>(k1);
        if (beats(oz, ok, z1, k1)) { z1 = oz; k1 = ok; }
    }
    {
        float oz = dpp_rorf<0x121>(z1); int ok = dpp_rori<0x121>(k1);
        if (beats(oz, ok, z1, k1)) { z1 = oz; k1 = ok; }
    }
}

// ---------- kernel A: pack W (640x512 f32) -> f16, B-fragment order ----------
// layout (16B units): idx = (k>>3)*640 + v ; within: (k&7)
__global__ void k_wsplit(const float* __restrict__ W, half8* __restrict__ W1p) {
    int t = blockIdx.x * 256 + threadIdx.x;
    if (t >= NV * (ND / 8)) return;
    int v  = t % NV;
    int kc = t / NV;
    const float* src = W + (size_t)v * ND + kc * 8;
    float4 p0 = *(const float4*)src;
    float4 p1 = *(const float4*)(src + 4);
    W1p[t] = cvt8hi(p0, p1);
}

// ---------- kernel B: f16 MFMA GEMM -> f16 logits ----------
// R15 structure + BK=128: stage 128 k per barrier (2 chunks), halving sync
// points 8 -> 4. B register double-buffer timing identical to R15 (chunk c+1's
// frags load during chunk c's 20 MFMAs). Accumulation order bit-identical.
// LDS rows 256 B, 16-B granule XOR swizzle (g8 ^ (row&15)).
#define AROWB2 256
__global__ __launch_bounds__(1024, 4) void k_gemm(
    const float* __restrict__ hidden,
    const half8* __restrict__ W1p,
    const float* __restrict__ bvec,
    _Float16* __restrict__ logits)
{
    __shared__ __align__(16) char Abuf[2][64 * AROWB2];   // 2 x 16 KB

    const int t    = threadIdx.x;
    const int lane = t & 63;
    const int w    = t >> 6;       // 0..15
    const int wn   = w & 7;        // col group (80 cols)
    const int wm   = w >> 3;       // row half (32 rows)
    const int l15  = lane & 15;
    const int l4   = lane >> 4;
    const int n0b  = blockIdx.x * 64;

    // staging role: thread stages 8 k-values (16 B as f16) of one row per 128-k step
    const int sm  = t >> 4;        // 0..63 token row
    const int sk8 = t & 15;        // 0..15 (8-k granule within 128)
    const float* hrow = hidden + (size_t)(n0b + sm) * ND + sk8 * 8;
    const int wbyte = sm * AROWB2 + ((sk8 ^ (sm & 15)) << 4);

    float4v acc[2][5];
    #pragma unroll
    for (int mt = 0; mt < 2; ++mt)
        #pragma unroll
        for (int nt = 0; nt < 5; ++nt) acc[mt][nt] = (float4v)0.0f;

    // prologue: stage double-chunk 0 (k 0..127)
    {
        float4 p0 = *(const float4*)(hrow);
        float4 p1 = *(const float4*)(hrow + 4);
        *(half8*)(&Abuf[0][wbyte]) = cvt8hi(p0, p1);
    }

    const half8* bbase = W1p + (size_t)l4 * NV + wn * 80 + l15;

    // preload chunk 0's B fragments (overlaps with the staging barrier)
    half8 bc[2][5], bn[2][5];
    #pragma unroll
    for (int ks = 0; ks < 2; ++ks)
        #pragma unroll
        for (int nt = 0; nt < 5; ++nt)
            bc[ks][nt] = bbase[(size_t)(ks * 4) * NV + nt * 16];

    __syncthreads();

    for (int c2 = 0; c2 < 4; ++c2) {
        float4 p0, p1;
        if (c2 < 3) {   // prefetch next 128-k of hidden
            p0 = *(const float4*)(hrow + (c2 + 1) * 128);
            p1 = *(const float4*)(hrow + (c2 + 1) * 128 + 4);
        }
        const char* base = Abuf[c2 & 1];

        // ---- chunk A = 2*c2 (k_local 0..63) ----
        // prefetch B for chunk 2*c2+1 (consumed below, after rotation)
        #pragma unroll
        for (int ks = 0; ks < 2; ++ks)
            #pragma unroll
            for (int nt = 0; nt < 5; ++nt)
                bn[ks][nt] = bbase[(size_t)((2 * c2 + 1) * 8 + ks * 4) * NV + nt * 16];

        #pragma unroll
        for (int ks = 0; ks < 2; ++ks) {
            const int xr = ((ks * 4 + l4) ^ l15) << 4;
            half8 fa[2];
            #pragma unroll
            for (int mt = 0; mt < 2; ++mt)
                fa[mt] = *(const half8*)(base + (wm * 32 + mt * 16 + l15) * AROWB2 + xr);
            #pragma unroll
            for (int nt = 0; nt < 5; ++nt)
                #pragma unroll
                for (int mt = 0; mt < 2; ++mt)
                    acc[mt][nt] = __builtin_amdgcn_mfma_f32_16x16x32_f16(fa[mt], bc[ks][nt], acc[mt][nt], 0, 0, 0);
        }
        #pragma unroll
        for (int ks = 0; ks < 2; ++ks)
            #pragma unroll
            for (int nt = 0; nt < 5; ++nt)
                bc[ks][nt] = bn[ks][nt];

        // ---- chunk B = 2*c2+1 (k_local 64..127) ----
        if (c2 < 3) {   // prefetch B for chunk 2*c2+2
            #pragma unroll
            for (int ks = 0; ks < 2; ++ks)
                #pragma unroll
                for (int nt = 0; nt < 5; ++nt)
                    bn[ks][nt] = bbase[(size_t)((2 * c2 + 2) * 8 + ks * 4) * NV + nt * 16];
        }

        #pragma unroll
        for (int ks = 0; ks < 2; ++ks) {
            const int xr = ((8 + ks * 4 + l4) ^ l15) << 4;
            half8 fa[2];
            #pragma unroll
            for (int mt = 0; mt < 2; ++mt)
                fa[mt] = *(const half8*)(base + (wm * 32 + mt * 16 + l15) * AROWB2 + xr);
            #pragma unroll
            for (int nt = 0; nt < 5; ++nt)
                #pragma unroll
                for (int mt = 0; mt < 2; ++mt)
                    acc[mt][nt] = __builtin_amdgcn_mfma_f32_16x16x32_f16(fa[mt], bc[ks][nt], acc[mt][nt], 0, 0, 0);
        }

        if (c2 < 3) {
            #pragma unroll
            for (int ks = 0; ks < 2; ++ks)
                #pragma unroll
                for (int nt = 0; nt < 5; ++nt)
                    bc[ks][nt] = bn[ks][nt];
            *(half8*)(&Abuf[(c2 + 1) & 1][wbyte]) = cvt8hi(p0, p1);
        }
        __syncthreads();
    }

    #pragma unroll
    for (int nt = 0; nt < 5; ++nt) {
        const int col = wn * 80 + nt * 16 + l15;
        const float bb = bvec[col];
        #pragma unroll
        for (int mt = 0; mt < 2; ++mt) {
            #pragma unroll
            for (int r = 0; r < 4; ++r) {
                const int row = n0b + wm * 32 + mt * 16 + l4 * 4 + r;
                logits[(size_t)row * NV + col] = (_Float16)(acc[mt][nt][r] + bb);
            }
        }
    }
}

// ---------- kernel C: streaming epilogue (R15 structure -- best measured) ----------
#define EPI_BLOCKS  1024
#define EPI_THREADS 256
#define EPI_SLOTS   (EPI_BLOCKS * (EPI_THREADS / 16))   // 16384
#define NPAIRS      (NTOK * NG)                          // 64000

__global__ __launch_bounds__(EPI_THREADS) void k_epi(
    const _Float16* __restrict__ logits,
    const float* __restrict__ gumbel,
    const int*   __restrict__ mask,
    const float* __restrict__ hidden,
    const float* __restrict__ W,
    const float* __restrict__ bvec,
    const float* __restrict__ codevec,
    float* __restrict__ out,
    float* __restrict__ marg_ws)
{
    __shared__ float marg[NV];
    const int t     = threadIdx.x;
    const int lane  = t & 63;
    const int q     = lane >> 4;
    const int ql    = lane & 15;
    const int wslot = blockIdx.x * (EPI_THREADS / 16) + (t >> 4);
    const int g     = wslot & 1;   // constant across grid-stride iterations

    for (int i = t; i < NV; i += EPI_THREADS) marg[i] = 0.f;
    __syncthreads();

    float mreg[5][4] = {};

    int pair = wslot;
    half4  ch[5];
    float4 cg[5];
    int    cm;
    {
        const _Float16* lrow = logits + (size_t)(pair >> 1) * NV + g * NK;
        const float*    grow = gumbel + (size_t)pair * NK;
        #pragma unroll
        for (int j = 0; j < 5; ++j) {
            ch[j] = *(const half4*)(lrow + 64 * j + 4 * ql);
            cg[j] = *(const float4*)(grow + 64 * j + 4 * ql);
        }
        cm = mask[pair >> 1];
    }

    while (true) {
        // ---- prefetch next pair (overlaps with current compute) ----
        const int npair = pair + EPI_SLOTS;
        const bool nvalid = npair < NPAIRS;
        half4  nh[5];
        float4 ng[5];
        int    nm = 0;
        if (nvalid) {
            const _Float16* lrow = logits + (size_t)(npair >> 1) * NV + g * NK;
            const float*    grow = gumbel + (size_t)npair * NK;
            #pragma unroll
            for (int j = 0; j < 5; ++j) {
                nh[j] = *(const half4*)(lrow + 64 * j + 4 * ql);
                ng[j] = *(const float4*)(grow + 64 * j + 4 * ql);
            }
            nm = mask[npair >> 1];
        }

        // ---- process current pair ----
        const int n = pair >> 1;

        // widen f16 logits to f32
        float lv[5][4];
        #pragma unroll
        for (int j = 0; j < 5; ++j)
            #pragma unroll
            for (int c = 0; c < 4; ++c)
                lv[j][c] = (float)ch[j][c];

        // soft_dist softmax of raw logits (|logit| small -> exp fp32-safe)
        float e[5][4];
        float s = 0.f;
        #pragma unroll
        for (int j = 0; j < 5; ++j) {
            e[j][0] = __expf(lv[j][0]); e[j][1] = __expf(lv[j][1]);
            e[j][2] = __expf(lv[j][2]); e[j][3] = __expf(lv[j][3]);
            s += (e[j][0] + e[j][1]) + (e[j][2] + e[j][3]);
        }
        s = qsum16(s);                      // DPP 16-lane sum
        const float pm = (cm != 0) ? (1.0f / s) : 0.0f;
        #pragma unroll
        for (int j = 0; j < 5; ++j)
            #pragma unroll
            for (int c = 0; c < 4; ++c)
                mreg[j][c] = fmaf(e[j][c], pm, mreg[j][c]);

        // z = logits + gumbel ; top-1 argmax (first-index tie-break)
        float z[5][4];
        #pragma unroll
        for (int j = 0; j < 5; ++j) {
            z[j][0] = lv[j][0] + cg[j].x;
            z[j][1] = lv[j][1] + cg[j].y;
            z[j][2] = lv[j][2] + cg[j].z;
            z[j][3] = lv[j][3] + cg[j].w;
        }
        float z1 = -3.4e38f; int k1 = 0;
        #pragma unroll
        for (int j = 0; j < 5; ++j)
            #pragma unroll
            for (int c = 0; c < 4; ++c) {
                const int idx = 64 * j + 4 * ql + c;
                if (z[j][c] > z1) { z1 = z[j][c]; k1 = idx; }
            }
        qargmax16(z1, k1);                  // DPP 16-lane argmax merge

        // near-tie detection: any element (!= k1) within TIE_THR of the max?
        bool flag = false;
        #pragma unroll
        for (int j = 0; j < 5; ++j)
            #pragma unroll
            for (int c = 0; c < 4; ++c) {
                const int idx = 64 * j + 4 * ql + c;
                flag |= (idx != k1) && (z[j][c] >= z1 - TIE_THR);
            }
        const unsigned long long bal = __ballot(flag);
        const unsigned int m16 = (unsigned int)((bal >> (q * 16)) & 0xFFFFull);

        int kbest = k1;
        if (m16) {
            // slow path (rare): exact runner-up, then fp64 refine from fp32 inputs
            float z2 = -3.4e38f; int k2 = 0x7fffffff;
            #pragma unroll
            for (int j = 0; j < 5; ++j)
                #pragma unroll
                for (int c = 0; c < 4; ++c) {
                    const int idx = 64 * j + 4 * ql + c;
                    const float zz = (idx == k1) ? -3.4e38f : z[j][c];
                    if (zz > z2) { z2 = zz; k2 = idx; }
                }
            #pragma unroll
            for (int off = 1; off < 16; off <<= 1) {
                float oz = __shfl_xor(z2, off, 16);
                int   ok = __shfl_xor(k2, off, 16);
                if (beats(oz, ok, z2, k2)) { z2 = oz; k2 = ok; }
            }
            if (z1 - z2 < TIE_THR) {
                const float* hr  = hidden + (size_t)n * ND;
                const float* w1r = W + ((size_t)g * NK + k1) * ND;
                const float* w2r = W + ((size_t)g * NK + k2) * ND;
                const float* grow = gumbel + (size_t)pair * NK;
                double s1 = 0.0, s2 = 0.0;
                #pragma unroll
                for (int j = 0; j < 32; ++j) {
                    const int idx = ql * 32 + j;
                    const double h = (double)hr[idx];
                    s1 += h * (double)w1r[idx];
                    s2 += h * (double)w2r[idx];
                }
                #pragma unroll
                for (int off = 8; off > 0; off >>= 1) {
                    s1 += __shfl_xor(s1, off, 16);
                    s2 += __shfl_xor(s2, off, 16);
                }
                const double zz1 = s1 + (double)bvec[g * NK + k1] + (double)grow[k1];
                const double zz2 = s2 + (double)bvec[g * NK + k2] + (double)grow[k2];
                const bool firstWins = (zz1 > zz2) || (zz1 == zz2 && k1 < k2);
                kbest = firstWins ? k1 : k2;
            }
        }

        // hard codevector gather: 128 floats = 32 float4, 16 lanes x 2
        const float4* cvrow = (const float4*)(codevec + ((size_t)g * NK + kbest) * NDCV);
        float4* dst = (float4*)(out + (size_t)n * (NG * NDCV) + g * NDCV);
        dst[ql]      = cvrow[ql];
        dst[ql + 16] = cvrow[ql + 16];

        if (!nvalid) break;
        pair = npair;
        cm = nm;
        #pragma unroll
        for (int j = 0; j < 5; ++j) { ch[j] = nh[j]; cg[j] = ng[j]; }
    }

    // ---- flush: LDS accumulate, then PLAIN coalesced stores (no atomics) ----
    #pragma unroll
    for (int j = 0; j < 5; ++j)
        #pragma unroll
        for (int c = 0; c < 4; ++c)
            atomicAdd(&marg[g * NK + 64 * j + 4 * ql + c], mreg[j][c]);
    __syncthreads();
    float* dstm = marg_ws + (size_t)blockIdx.x * NV;
    for (int i = t; i < NV; i += EPI_THREADS) dstm[i] = marg[i];
}

// ---------- kernel C2: sum 1024 per-block partials -> marginal[640] ----------
__global__ __launch_bounds__(256) void k_reduce(
    const float* __restrict__ marg_ws, float* __restrict__ marginal)
{
    __shared__ float red[8][32];
    const int v  = blockIdx.x * 32 + (threadIdx.x & 31);
    const int ch = threadIdx.x >> 5;   // 0..7

    float s = 0.f;
    for (int i = 0; i < EPI_BLOCKS / 8; ++i)
        s += marg_ws[(size_t)(ch * (EPI_BLOCKS / 8) + i) * NV + v];

    red[ch][threadIdx.x & 31] = s;
    __syncthreads();
    if (ch == 0) {
        float tot = s;
        #pragma unroll
        for (int c = 1; c < 8; ++c) tot += red[c][threadIdx.x & 31];
        marginal[v] = tot;
    }
}

// ---------- shared: perplexity finalize ----------
__global__ __launch_bounds__(NTHREADS) void k_finalize(
    const int* __restrict__ mask,
    const float* __restrict__ marginal,
    float* __restrict__ ppl_out)
{
    __shared__ float red[16];
    const int tid  = threadIdx.x;
    const int wave = tid >> 6;
    const int lane = tid & 63;

    float cnt = 0.f;
    for (int i = tid; i < NTOK; i += NTHREADS) cnt += (mask[i] != 0) ? 1.f : 0.f;
    #pragma unroll
    for (int off = 32; off > 0; off >>= 1) cnt += __shfl_xor(cnt, off);
    if (lane == 0) red[wave] = cnt;
    __syncthreads();
    float total = 0.f;
    #pragma unroll
    for (int wv = 0; wv < 10; wv++) total += red[wv];
    __syncthreads();

    float p = marginal[tid] / total;
    float val = p * logf(p + EPSF);
    #pragma unroll
    for (int off = 32; off > 0; off >>= 1) val += __shfl_xor(val, off);
    if (lane == 0) red[wave] = val;
    __syncthreads();
    if (tid == 0) {
        float h0 = red[0] + red[1] + red[2] + red[3] + red[4];
        float h1 = red[5] + red[6] + red[7] + red[8] + red[9];
        ppl_out[0] = expf(-h0) + expf(-h1);
    }
}

// ================= fallback path (round-1 fp32 kernels) =================
__global__ void k_transpose(const float* __restrict__ W, float* __restrict__ WT) {
    int idx = blockIdx.x * 256 + threadIdx.x;
    if (idx >= ND * NV) return;
    int k = idx / NV;
    int v = idx - k * NV;
    WT[idx] = W[v * ND + k];
}

__global__ __launch_bounds__(NTHREADS) void k_main_fb(
    const float* __restrict__ hidden,
    const int*   __restrict__ mask,
    const float* __restrict__ bvec,
    const float* __restrict__ WT,
    const float* __restrict__ codevec,
    const float* __restrict__ gumbel,
    float* __restrict__ out,
    float* __restrict__ marginal)
{
    __shared__ float smem[TPB * NV];
    __shared__ float marg_lds[NV];

    const int tid = threadIdx.x;
    const int n0  = blockIdx.x * TPB;

    marg_lds[tid] = 0.0f;
    {
        const float4* src = (const float4*)(hidden + (size_t)n0 * ND);
        float4* dst = (float4*)smem;
        for (int i = tid; i < TPB * ND / 4; i += NTHREADS) dst[i] = src[i];
    }
    __syncthreads();

    const int vgroup = tid % 160;
    const int tgroup = tid / 160;
    const int v0 = vgroup * 4;
    const int t0 = tgroup * 4;

    float acc[4][4] = {};
    const float* hbase = smem + t0 * ND;

    for (int k = 0; k < ND; k += 4) {
        float wv_[4][4], h[4][4];
        #pragma unroll
        for (int i = 0; i < 4; i++) {
            float4 tw = *(const float4*)(WT + (size_t)(k + i) * NV + v0);
            wv_[i][0] = tw.x; wv_[i][1] = tw.y; wv_[i][2] = tw.z; wv_[i][3] = tw.w;
        }
        #pragma unroll
        for (int i = 0; i < 4; i++) {
            float4 th = *(const float4*)(hbase + i * ND + k);
            h[i][0] = th.x; h[i][1] = th.y; h[i][2] = th.z; h[i][3] = th.w;
        }
        #pragma unroll
        for (int kk = 0; kk < 4; kk++)
            #pragma unroll
            for (int ti = 0; ti < 4; ti++)
                #pragma unroll
                for (int vi = 0; vi < 4; vi++)
                    acc[ti][vi] = fmaf(h[ti][kk], wv_[kk][vi], acc[ti][vi]);
    }

    __syncthreads();

    #pragma unroll
    for (int ti = 0; ti < 4; ti++) {
        float4 lv;
        lv.x = acc[ti][0] + bvec[v0 + 0];
        lv.y = acc[ti][1] + bvec[v0 + 1];
        lv.z = acc[ti][2] + bvec[v0 + 2];
        lv.w = acc[ti][3] + bvec[v0 + 3];
        *(float4*)(smem + (size_t)(t0 + ti) * NV + v0) = lv;
    }
    __syncthreads();

    const int wave = tid >> 6;
    const int lane = tid & 63;
    const int g = wave & 1;
    float marg_reg[5] = {0.f, 0.f, 0.f, 0.f, 0.f};

    for (int pair = wave; pair < 2 * TPB; pair += 10) {
        const int tt = pair >> 1;
        const int n = n0 + tt;
        const float* lrow = smem + tt * NV + g * NK;

        float lv[5];
        #pragma unroll
        for (int j = 0; j < 5; j++) lv[j] = lrow[lane + 64 * j];

        float m = lv[0];
        #pragma unroll
        for (int j = 1; j < 5; j++) m = fmaxf(m, lv[j]);
        #pragma unroll
        for (int off = 32; off > 0; off >>= 1) m = fmaxf(m, __shfl_xor(m, off));

        float e[5], s = 0.f;
        #pragma unroll
        for (int j = 0; j < 5; j++) { e[j] = expf(lv[j] - m); s += e[j]; }
        #pragma unroll
        for (int off = 32; off > 0; off >>= 1) s += __shfl_xor(s, off);
        const float inv = 1.0f / s;

        if (mask[n] != 0) {
            #pragma unroll
            for (int j = 0; j < 5; j++) marg_reg[j] += e[j] * inv;
        }

        const float* grow = gumbel + ((size_t)n * NG + g) * NK;
        float zbest = -3.4e38f;
        int kbest = 0;
        #pragma unroll
        for (int j = 0; j < 5; j++) {
            float z = lv[j] + grow[lane + 64 * j];
            if (z > zbest) { zbest = z; kbest = lane + 64 * j; }
        }
        #pragma unroll
        for (int off = 32; off > 0; off >>= 1) {
            float zo = __shfl_xor(zbest, off);
            int ko = __shfl_xor(kbest, off);
            if (zo > zbest || (zo == zbest && ko < kbest)) { zbest = zo; kbest = ko; }
        }

        const float2* cvrow = (const float2*)(codevec + ((size_t)g * NK + kbest) * NDCV);
        float2* dstrow = (float2*)(out + (size_t)n * (NG * NDCV) + g * NDCV);
        dstrow[lane] = cvrow[lane];
    }

    #pragma unroll
    for (int j = 0; j < 5; j++)
        atomicAdd(&marg_lds[g * NK + lane + 64 * j], marg_reg[j]);
    __syncthreads();
    atomicAdd(&marginal[tid], marg_lds[tid]);
}

// ================= launch =================
extern "C" void kernel_launch(void* const* d_in, const int* in_sizes, int n_in,
                              void* d_out, int out_size, void* d_ws, size_t ws_size,
                              hipStream_t stream) {
    const float* hidden  = (const float*)d_in[0];
    const int*   mask    = (const int*)  d_in[1];
    const float* W       = (const float*)d_in[2];
    const float* bvec    = (const float*)d_in[3];
    const float* codevec = (const float*)d_in[4];
    const float* gumbel  = (const float*)d_in[5];
    float* out = (float*)d_out;

    float* marginal = (float*)d_ws;                       // 640 f32 @ 0

    const size_t off_w1     = 4096;
    const size_t off_logits = 2u * 1024u * 1024u;
    const size_t off_margws = 44u * 1024u * 1024u;        // after 41 MB f16 logits
    const size_t need = off_margws + (size_t)EPI_BLOCKS * NV * 4;   // ~46.6 MB

    hipMemsetAsync(marginal, 0, NV * sizeof(float), stream);

    if (ws_size >= need) {
        half8*    W1p     = (half8*)((char*)d_ws + off_w1);
        _Float16* logits  = (_Float16*)((char*)d_ws + off_logits);
        float*    marg_ws = (float*)((char*)d_ws + off_margws);

        k_wsplit<<<(NV * (ND / 8) + 255) / 256, 256, 0, stream>>>(W, W1p);
        k_gemm<<<NTOK / 64, 1024, 0, stream>>>(hidden, W1p, bvec, logits);
        k_epi<<<EPI_BLOCKS, EPI_THREADS, 0, stream>>>(logits, gumbel, mask, hidden, W, bvec,
                                                      codevec, out, marg_ws);
        k_reduce<<<NV / 32, 256, 0, stream>>>(marg_ws, marginal);
    } else {
        float* WT = (float*)d_ws + 1024;
        k_transpose<<<(ND * NV + 255) / 256, 256, 0, stream>>>(W, WT);
        k_main_fb<<<NTOK / TPB, NTHREADS, 0, stream>>>(hidden, mask, bvec, WT, codevec,
                                                       gumbel, out, marginal);
    }
    k_finalize<<<1, NTHREADS, 0, stream>>>(mask, marginal, out + (size_t)NTOK * NG * NDCV);
}

// Round 18
// 123.554 us; speedup vs baseline: 1.0164x; 1.0164x over previous
//
#include <hip/hip_runtime.h>

// Problem constants
#define NB    16
#define NS    2000
#define ND    512      // input dim
#define NG    2        // groups
#define NK    320      // vars per group
#define NV    640      // G*K
#define NDCV  128      // per-group codevector dim
#define NTOK  32000    // B*S
#define TAUF  2.0f
#define EPSF  1e-7f

#define TPB      16
#define NTHREADS 640
#define TIE_THR  4.0e-3f   // covers f16-GEMM err + f16 logits storage err

using half8   = __attribute__((ext_vector_type(8))) _Float16;
using half4   = __attribute__((ext_vector_type(4))) _Float16;
using float4v = __attribute__((ext_vector_type(4))) float;

__device__ inline half8 cvt8hi(float4 p0, float4 p1) {
    half8 a;
    a[0] = (_Float16)p0.x; a[1] = (_Float16)p0.y;
    a[2] = (_Float16)p0.z; a[3] = (_Float16)p0.w;
    a[4] = (_Float16)p1.x; a[5] = (_Float16)p1.y;
    a[6] = (_Float16)p1.z; a[7] = (_Float16)p1.w;
    return a;
}

__device__ inline half4 cvt4hi(float4 p) {
    half4 a;
    a[0] = (_Float16)p.x; a[1] = (_Float16)p.y;
    a[2] = (_Float16)p.z; a[3] = (_Float16)p.w;
    return a;
}

__device__ inline bool beats(float za, int ka, float zb, int kb) {
    return (za > zb) || (za == zb && ka < kb);
}

// ---- DPP 16-lane (row) rotations: VALU-pipe lane exchange. row_ror:N = 0x120|N.
template <int CTRL>
__device__ __forceinline__ float dpp_rorf(float x) {
    return __int_as_float(__builtin_amdgcn_update_dpp(
        __float_as_int(x), __float_as_int(x), CTRL, 0xF, 0xF, false));
}
template <int CTRL>
__device__ __forceinline__ int dpp_rori(int x) {
    return __builtin_amdgcn_update_dpp(x, x, CTRL, 0xF, 0xF, false);
}

__device__ __forceinline__ float qsum16(float s) {
    s += dpp_rorf<0x128>(s);
    s += dpp_rorf<0x124>(s);
    s += dpp_rorf<0x122>(s);
    s += dpp_rorf<0x121>(s);
    return s;
}

__device__ __forceinline__ void qargmax16(float& z1, int& k1) {
    {
        float oz = dpp_rorf<0x128>(z1); int ok = dpp_rori<0x128>(k1);
        if (beats(oz, ok, z1, k1)) { z1 = oz; k1 = ok; }
    }
    {
        float oz = dpp_rorf<0x124>(z1); int ok = dpp_rori<0x124>(k1);
        if (beats(oz, ok, z1, k1)) { z1 = oz; k1 = ok; }
    }
    {
        float oz = dpp_rorf<0x122>(z1); int ok = dpp_rori<0x122>(k1);
        if (beats(oz, ok, z1, k1)) { z1 = oz; k1 = ok; }
    }
    {
        float oz = dpp_rorf<0x121>(z1); int ok = dpp_rori<0x121>(k1);
        if (beats(oz, ok, z1, k1)) { z1 = oz; k1 = ok; }
    }
}

// ---------- kernel A: pack W (640x512 f32) -> f16, B-fragment order ----------
// layout (16B units): idx = (k>>3)*640 + v ; within: (k&7)
__global__ void k_wsplit(const float* __restrict__ W, half8* __restrict__ W1p) {
    int t = blockIdx.x * 256 + threadIdx.x;
    if (t >= NV * (ND / 8)) return;
    int v  = t % NV;
    int kc = t / NV;
    const float* src = W + (size_t)v * ND + kc * 8;
    float4 p0 = *(const float4*)src;
    float4 p1 = *(const float4*)(src + 4);
    W1p[t] = cvt8hi(p0, p1);
}

// ---------- kernel B: f16 MFMA GEMM -> f16 logits (R15 structure, B reg-dbuf) ----------
// BM=64 tokens/block, full N=640, 16 waves, BK=64 double-buffered LDS with
// 8B-granule XOR swizzle, plus register double-buffer for the 10 B fragments
// per chunk (chunk c+1's frags load during chunk c's 20 MFMAs). Best measured.
#define AROWB 128
__global__ __launch_bounds__(1024, 4) void k_gemm(
    const float* __restrict__ hidden,
    const half8* __restrict__ W1p,
    const float* __restrict__ bvec,
    _Float16* __restrict__ logits)
{
    __shared__ __align__(16) char Abuf[2][64 * AROWB];   // 2 x 8 KB

    const int t    = threadIdx.x;
    const int lane = t & 63;
    const int w    = t >> 6;       // 0..15
    const int wn   = w & 7;        // col group (80 cols)
    const int wm   = w >> 3;       // row half (32 rows)
    const int l15  = lane & 15;
    const int l4   = lane >> 4;
    const int n0b  = blockIdx.x * 64;

    // staging role: thread stages 4 k-values (8B) of one row per chunk
    const int sm  = t >> 4;        // 0..63 token row
    const int sk4 = t & 15;        // 0..15 (4-k granule)
    const float* hrow = hidden + (size_t)(n0b + sm) * ND + sk4 * 4;
    const int wbyte = sm * AROWB + ((((sk4 >> 1) ^ (sm & 7)) << 4) | ((sk4 & 1) << 3));

    float4v acc[2][5];
    #pragma unroll
    for (int mt = 0; mt < 2; ++mt)
        #pragma unroll
        for (int nt = 0; nt < 5; ++nt) acc[mt][nt] = (float4v)0.0f;

    // prologue: stage chunk 0
    {
        float4 p = *(const float4*)(hrow);
        *(half4*)(&Abuf[0][wbyte]) = cvt4hi(p);
    }

    const half8* bbase = W1p + (size_t)l4 * NV + wn * 80 + l15;

    // preload chunk 0's B fragments (overlaps with the staging barrier)
    half8 bc[2][5], bn[2][5];
    #pragma unroll
    for (int ks = 0; ks < 2; ++ks)
        #pragma unroll
        for (int nt = 0; nt < 5; ++nt)
            bc[ks][nt] = bbase[(size_t)(ks * 4) * NV + nt * 16];

    __syncthreads();

    for (int c = 0; c < 8; ++c) {
        float4 p;
        if (c < 7) {
            p = *(const float4*)(hrow + (c + 1) * 64);   // prefetch next hidden chunk
            // prefetch next chunk's B fragments (consumed after the barrier)
            #pragma unroll
            for (int ks = 0; ks < 2; ++ks)
                #pragma unroll
                for (int nt = 0; nt < 5; ++nt)
                    bn[ks][nt] = bbase[(size_t)((c + 1) * 8 + ks * 4) * NV + nt * 16];
        }

        const char* base = Abuf[c & 1];
        #pragma unroll
        for (int ks = 0; ks < 2; ++ks) {
            const int xr = ((ks * 4 + l4) ^ (l15 & 7)) << 4;
            half8 fa[2];
            #pragma unroll
            for (int mt = 0; mt < 2; ++mt)
                fa[mt] = *(const half8*)(base + (wm * 32 + mt * 16 + l15) * AROWB + xr);

            #pragma unroll
            for (int nt = 0; nt < 5; ++nt)
                #pragma unroll
                for (int mt = 0; mt < 2; ++mt)
                    acc[mt][nt] = __builtin_amdgcn_mfma_f32_16x16x32_f16(fa[mt], bc[ks][nt], acc[mt][nt], 0, 0, 0);
        }

        if (c < 7) {
            *(half4*)(&Abuf[(c + 1) & 1][wbyte]) = cvt4hi(p);
            // rotate B double-buffer (compile-time indices, plain moves)
            #pragma unroll
            for (int ks = 0; ks < 2; ++ks)
                #pragma unroll
                for (int nt = 0; nt < 5; ++nt)
                    bc[ks][nt] = bn[ks][nt];
        }
        __syncthreads();
    }

    #pragma unroll
    for (int nt = 0; nt < 5; ++nt) {
        const int col = wn * 80 + nt * 16 + l15;
        const float bb = bvec[col];
        #pragma unroll
        for (int mt = 0; mt < 2; ++mt) {
            #pragma unroll
            for (int r = 0; r < 4; ++r) {
                const int row = n0b + wm * 32 + mt * 16 + l4 * 4 + r;
                logits[(size_t)row * NV + col] = (_Float16)(acc[mt][nt][r] + bb);
            }
        }
    }
}

// ---------- kernel C: streaming epilogue (R15 structure -- best measured) ----------
// One pair per 16-lane quarter-slot, grid-stride with depth-1 register prefetch.
// Slot stride even -> g constant per thread -> marginal in registers; DPP
// reductions; atomic-free flush to per-block partials.
#define EPI_BLOCKS  1024
#define EPI_THREADS 256
#define EPI_SLOTS   (EPI_BLOCKS * (EPI_THREADS / 16))   // 16384
#define NPAIRS      (NTOK * NG)                          // 64000

__global__ __launch_bounds__(EPI_THREADS) void k_epi(
    const _Float16* __restrict__ logits,
    const float* __restrict__ gumbel,
    const int*   __restrict__ mask,
    const float* __restrict__ hidden,
    const float* __restrict__ W,
    const float* __restrict__ bvec,
    const float* __restrict__ codevec,
    float* __restrict__ out,
    float* __restrict__ marg_ws)
{
    __shared__ float marg[NV];
    const int t     = threadIdx.x;
    const int lane  = t & 63;
    const int q     = lane >> 4;
    const int ql    = lane & 15;
    const int wslot = blockIdx.x * (EPI_THREADS / 16) + (t >> 4);
    const int g     = wslot & 1;   // constant across grid-stride iterations

    for (int i = t; i < NV; i += EPI_THREADS) marg[i] = 0.f;
    __syncthreads();

    float mreg[5][4] = {};

    int pair = wslot;
    half4  ch[5];
    float4 cg[5];
    int    cm;
    {
        const _Float16* lrow = logits + (size_t)(pair >> 1) * NV + g * NK;
        const float*    grow = gumbel + (size_t)pair * NK;
        #pragma unroll
        for (int j = 0; j < 5; ++j) {
            ch[j] = *(const half4*)(lrow + 64 * j + 4 * ql);
            cg[j] = *(const float4*)(grow + 64 * j + 4 * ql);
        }
        cm = mask[pair >> 1];
    }

    while (true) {
        // ---- prefetch next pair (overlaps with current compute) ----
        const int npair = pair + EPI_SLOTS;
        const bool nvalid = npair < NPAIRS;
        half4  nh[5];
        float4 ng[5];
        int    nm = 0;
        if (nvalid) {
            const _Float16* lrow = logits + (size_t)(npair >> 1) * NV + g * NK;
            const float*    grow = gumbel + (size_t)npair * NK;
            #pragma unroll
            for (int j = 0; j < 5; ++j) {
                nh[j] = *(const half4*)(lrow + 64 * j + 4 * ql);
                ng[j] = *(const float4*)(grow + 64 * j + 4 * ql);
            }
            nm = mask[npair >> 1];
        }

        // ---- process current pair ----
        const int n = pair >> 1;

        // widen f16 logits to f32
        float lv[5][4];
        #pragma unroll
        for (int j = 0; j < 5; ++j)
            #pragma unroll
            for (int c = 0; c < 4; ++c)
                lv[j][c] = (float)ch[j][c];

        // soft_dist softmax of raw logits (|logit| small -> exp fp32-safe)
        float e[5][4];
        float s = 0.f;
        #pragma unroll
        for (int j = 0; j < 5; ++j) {
            e[j][0] = __expf(lv[j][0]); e[j][1] = __expf(lv[j][1]);
            e[j][2] = __expf(lv[j][2]); e[j][3] = __expf(lv[j][3]);
            s += (e[j][0] + e[j][1]) + (e[j][2] + e[j][3]);
        }
        s = qsum16(s);                      // DPP 16-lane sum
        const float pm = (cm != 0) ? (1.0f / s) : 0.0f;
        #pragma unroll
        for (int j = 0; j < 5; ++j)
            #pragma unroll
            for (int c = 0; c < 4; ++c)
                mreg[j][c] = fmaf(e[j][c], pm, mreg[j][c]);

        // z = logits + gumbel ; top-1 argmax (first-index tie-break)
        float z[5][4];
        #pragma unroll
        for (int j = 0; j < 5; ++j) {
            z[j][0] = lv[j][0] + cg[j].x;
            z[j][1] = lv[j][1] + cg[j].y;
            z[j][2] = lv[j][2] + cg[j].z;
            z[j][3] = lv[j][3] + cg[j].w;
        }
        float z1 = -3.4e38f; int k1 = 0;
        #pragma unroll
        for (int j = 0; j < 5; ++j)
            #pragma unroll
            for (int c = 0; c < 4; ++c) {
                const int idx = 64 * j + 4 * ql + c;
                if (z[j][c] > z1) { z1 = z[j][c]; k1 = idx; }
            }
        qargmax16(z1, k1);                  // DPP 16-lane argmax merge

        // near-tie detection: any element (!= k1) within TIE_THR of the max?
        bool flag = false;
        #pragma unroll
        for (int j = 0; j < 5; ++j)
            #pragma unroll
            for (int c = 0; c < 4; ++c) {
                const int idx = 64 * j + 4 * ql + c;
                flag |= (idx != k1) && (z[j][c] >= z1 - TIE_THR);
            }
        const unsigned long long bal = __ballot(flag);
        const unsigned int m16 = (unsigned int)((bal >> (q * 16)) & 0xFFFFull);

        int kbest = k1;
        if (m16) {
            // slow path (rare): exact runner-up, then fp64 refine from fp32 inputs
            float z2 = -3.4e38f; int k2 = 0x7fffffff;
            #pragma unroll
            for (int j = 0; j < 5; ++j)
                #pragma unroll
                for (int c = 0; c < 4; ++c) {
                    const int idx = 64 * j + 4 * ql + c;
                    const float zz = (idx == k1) ? -3.4e38f : z[j][c];
                    if (zz > z2) { z2 = zz; k2 = idx; }
                }
            #pragma unroll
            for (int off = 1; off < 16; off <<= 1) {
                float oz = __shfl_xor(z2, off, 16);
                int   ok = __shfl_xor(k2, off, 16);
                if (beats(oz, ok, z2, k2)) { z2 = oz; k2 = ok; }
            }
            if (z1 - z2 < TIE_THR) {
                const float* hr  = hidden + (size_t)n * ND;
                const float* w1r = W + ((size_t)g * NK + k1) * ND;
                const float* w2r = W + ((size_t)g * NK + k2) * ND;
                const float* grow = gumbel + (size_t)pair * NK;
                double s1 = 0.0, s2 = 0.0;
                #pragma unroll
                for (int j = 0; j < 32; ++j) {
                    const int idx = ql * 32 + j;
                    const double h = (double)hr[idx];
                    s1 += h * (double)w1r[idx];
                    s2 += h * (double)w2r[idx];
                }
                #pragma unroll
                for (int off = 8; off > 0; off >>= 1) {
                    s1 += __shfl_xor(s1, off, 16);
                    s2 += __shfl_xor(s2, off, 16);
                }
                const double zz1 = s1 + (double)bvec[g * NK + k1] + (double)grow[k1];
                const double zz2 = s2 + (double)bvec[g * NK + k2] + (double)grow[k2];
                const bool firstWins = (zz1 > zz2) || (zz1 == zz2 && k1 < k2);
                kbest = firstWins ? k1 : k2;
            }
        }

        // hard codevector gather: 128 floats = 32 float4, 16 lanes x 2
        const float4* cvrow = (const float4*)(codevec + ((size_t)g * NK + kbest) * NDCV);
        float4* dst = (float4*)(out + (size_t)n * (NG * NDCV) + g * NDCV);
        dst[ql]      = cvrow[ql];
        dst[ql + 16] = cvrow[ql + 16];

        if (!nvalid) break;
        pair = npair;
        cm = nm;
        #pragma unroll
        for (int j = 0; j < 5; ++j) { ch[j] = nh[j]; cg[j] = ng[j]; }
    }

    // ---- flush: LDS accumulate, then PLAIN coalesced stores (no atomics) ----
    #pragma unroll
    for (int j = 0; j < 5; ++j)
        #pragma unroll
        for (int c = 0; c < 4; ++c)
            atomicAdd(&marg[g * NK + 64 * j + 4 * ql + c], mreg[j][c]);
    __syncthreads();
    float* dstm = marg_ws + (size_t)blockIdx.x * NV;
    for (int i = t; i < NV; i += EPI_THREADS) dstm[i] = marg[i];
}

// ---------- kernel C2: sum 1024 per-block partials -> marginal[640] ----------
__global__ __launch_bounds__(256) void k_reduce(
    const float* __restrict__ marg_ws, float* __restrict__ marginal)
{
    __shared__ float red[8][32];
    const int v  = blockIdx.x * 32 + (threadIdx.x & 31);
    const int ch = threadIdx.x >> 5;   // 0..7

    float s = 0.f;
    for (int i = 0; i < EPI_BLOCKS / 8; ++i)
        s += marg_ws[(size_t)(ch * (EPI_BLOCKS / 8) + i) * NV + v];

    red[ch][threadIdx.x & 31] = s;
    __syncthreads();
    if (ch == 0) {
        float tot = s;
        #pragma unroll
        for (int c = 1; c < 8; ++c) tot += red[c][threadIdx.x & 31];
        marginal[v] = tot;
    }
}

// ---------- shared: perplexity finalize ----------
__global__ __launch_bounds__(NTHREADS) void k_finalize(
    const int* __restrict__ mask,
    const float* __restrict__ marginal,
    float* __restrict__ ppl_out)
{
    __shared__ float red[16];
    const int tid  = threadIdx.x;
    const int wave = tid >> 6;
    const int lane = tid & 63;

    float cnt = 0.f;
    for (int i = tid; i < NTOK; i += NTHREADS) cnt += (mask[i] != 0) ? 1.f : 0.f;
    #pragma unroll
    for (int off = 32; off > 0; off >>= 1) cnt += __shfl_xor(cnt, off);
    if (lane == 0) red[wave] = cnt;
    __syncthreads();
    float total = 0.f;
    #pragma unroll
    for (int wv = 0; wv < 10; wv++) total += red[wv];
    __syncthreads();

    float p = marginal[tid] / total;
    float val = p * logf(p + EPSF);
    #pragma unroll
    for (int off = 32; off > 0; off >>= 1) val += __shfl_xor(val, off);
    if (lane == 0) red[wave] = val;
    __syncthreads();
    if (tid == 0) {
        float h0 = red[0] + red[1] + red[2] + red[3] + red[4];
        float h1 = red[5] + red[6] + red[7] + red[8] + red[9];
        ppl_out[0] = expf(-h0) + expf(-h1);
    }
}

// ================= fallback path (round-1 fp32 kernels) =================
__global__ void k_transpose(const float* __restrict__ W, float* __restrict__ WT) {
    int idx = blockIdx.x * 256 + threadIdx.x;
    if (idx >= ND * NV) return;
    int k = idx / NV;
    int v = idx - k * NV;
    WT[idx] = W[v * ND + k];
}

__global__ __launch_bounds__(NTHREADS) void k_main_fb(
    const float* __restrict__ hidden,
    const int*   __restrict__ mask,
    const float* __restrict__ bvec,
    const float* __restrict__ WT,
    const float* __restrict__ codevec,
    const float* __restrict__ gumbel,
    float* __restrict__ out,
    float* __restrict__ marginal)
{
    __shared__ float smem[TPB * NV];
    __shared__ float marg_lds[NV];

    const int tid = threadIdx.x;
    const int n0  = blockIdx.x * TPB;

    marg_lds[tid] = 0.0f;
    {
        const float4* src = (const float4*)(hidden + (size_t)n0 * ND);
        float4* dst = (float4*)smem;
        for (int i = tid; i < TPB * ND / 4; i += NTHREADS) dst[i] = src[i];
    }
    __syncthreads();

    const int vgroup = tid % 160;
    const int tgroup = tid / 160;
    const int v0 = vgroup * 4;
    const int t0 = tgroup * 4;

    float acc[4][4] = {};
    const float* hbase = smem + t0 * ND;

    for (int k = 0; k < ND; k += 4) {
        float wv_[4][4], h[4][4];
        #pragma unroll
        for (int i = 0; i < 4; i++) {
            float4 tw = *(const float4*)(WT + (size_t)(k + i) * NV + v0);
            wv_[i][0] = tw.x; wv_[i][1] = tw.y; wv_[i][2] = tw.z; wv_[i][3] = tw.w;
        }
        #pragma unroll
        for (int i = 0; i < 4; i++) {
            float4 th = *(const float4*)(hbase + i * ND + k);
            h[i][0] = th.x; h[i][1] = th.y; h[i][2] = th.z; h[i][3] = th.w;
        }
        #pragma unroll
        for (int kk = 0; kk < 4; kk++)
            #pragma unroll
            for (int ti = 0; ti < 4; ti++)
                #pragma unroll
                for (int vi = 0; vi < 4; vi++)
                    acc[ti][vi] = fmaf(h[ti][kk], wv_[kk][vi], acc[ti][vi]);
    }

    __syncthreads();

    #pragma unroll
    for (int ti = 0; ti < 4; ti++) {
        float4 lv;
        lv.x = acc[ti][0] + bvec[v0 + 0];
        lv.y = acc[ti][1] + bvec[v0 + 1];
        lv.z = acc[ti][2] + bvec[v0 + 2];
        lv.w = acc[ti][3] + bvec[v0 + 3];
        *(float4*)(smem + (size_t)(t0 + ti) * NV + v0) = lv;
    }
    __syncthreads();

    const int wave = tid >> 6;
    const int lane = tid & 63;
    const int g = wave & 1;
    float marg_reg[5] = {0.f, 0.f, 0.f, 0.f, 0.f};

    for (int pair = wave; pair < 2 * TPB; pair += 10) {
        const int tt = pair >> 1;
        const int n = n0 + tt;
        const float* lrow = smem + tt * NV + g * NK;

        float lv[5];
        #pragma unroll
        for (int j = 0; j < 5; j++) lv[j] = lrow[lane + 64 * j];

        float m = lv[0];
        #pragma unroll
        for (int j = 1; j < 5; j++) m = fmaxf(m, lv[j]);
        #pragma unroll
        for (int off = 32; off > 0; off >>= 1) m = fmaxf(m, __shfl_xor(m, off));

        float e[5], s = 0.f;
        #pragma unroll
        for (int j = 0; j < 5; j++) { e[j] = expf(lv[j] - m); s += e[j]; }
        #pragma unroll
        for (int off = 32; off > 0; off >>= 1) s += __shfl_xor(s, off);
        const float inv = 1.0f / s;

        if (mask[n] != 0) {
            #pragma unroll
            for (int j = 0; j < 5; j++) marg_reg[j] += e[j] * inv;
        }

        const float* grow = gumbel + ((size_t)n * NG + g) * NK;
        float zbest = -3.4e38f;
        int kbest = 0;
        #pragma unroll
        for (int j = 0; j < 5; j++) {
            float z = lv[j] + grow[lane + 64 * j];
            if (z > zbest) { zbest = z; kbest = lane + 64 * j; }
        }
        #pragma unroll
        for (int off = 32; off > 0; off >>= 1) {
            float zo = __shfl_xor(zbest, off);
            int ko = __shfl_xor(kbest, off);
            if (zo > zbest || (zo == zbest && ko < kbest)) { zbest = zo; kbest = ko; }
        }

        const float2* cvrow = (const float2*)(codevec + ((size_t)g * NK + kbest) * NDCV);
        float2* dstrow = (float2*)(out + (size_t)n * (NG * NDCV) + g * NDCV);
        dstrow[lane] = cvrow[lane];
    }

    #pragma unroll
    for (int j = 0; j < 5; j++)
        atomicAdd(&marg_lds[g * NK + lane + 64 * j], marg_reg[j]);
    __syncthreads();
    atomicAdd(&marginal[tid], marg_lds[tid]);
}

// ================= launch =================
extern "C" void kernel_launch(void* const* d_in, const int* in_sizes, int n_in,
                              void* d_out, int out_size, void* d_ws, size_t ws_size,
                              hipStream_t stream) {
    const float* hidden  = (const float*)d_in[0];
    const int*   mask    = (const int*)  d_in[1];
    const float* W       = (const float*)d_in[2];
    const float* bvec    = (const float*)d_in[3];
    const float* codevec = (const float*)d_in[4];
    const float* gumbel  = (const float*)d_in[5];
    float* out = (float*)d_out;

    float* marginal = (float*)d_ws;                       // 640 f32 @ 0

    const size_t off_w1     = 4096;
    const size_t off_logits = 2u * 1024u * 1024u;
    const size_t off_margws = 44u * 1024u * 1024u;        // after 41 MB f16 logits
    const size_t need = off_margws + (size_t)EPI_BLOCKS * NV * 4;   // ~46.6 MB

    hipMemsetAsync(marginal, 0, NV * sizeof(float), stream);

    if (ws_size >= need) {
        half8*    W1p     = (half8*)((char*)d_ws + off_w1);
        _Float16* logits  = (_Float16*)((char*)d_ws + off_logits);
        float*    marg_ws = (float*)((char*)d_ws + off_margws);

        k_wsplit<<<(NV * (ND / 8) + 255) / 256, 256, 0, stream>>>(W, W1p);
        k_gemm<<<NTOK / 64, 1024, 0, stream>>>(hidden, W1p, bvec, logits);
        k_epi<<<EPI_BLOCKS, EPI_THREADS, 0, stream>>>(logits, gumbel, mask, hidden, W, bvec,
                                                      codevec, out, marg_ws);
        k_reduce<<<NV / 32, 256, 0, stream>>>(marg_ws, marginal);
    } else {
        float* WT = (float*)d_ws + 1024;
        k_transpose<<<(ND * NV + 255) / 256, 256, 0, stream>>>(W, WT);
        k_main_fb<<<NTOK / TPB, NTHREADS, 0, stream>>>(hidden, mask, bvec, WT, codevec,
                                                       gumbel, out, marginal);
    }
    k_finalize<<<1, NTHREADS, 0, stream>>>(mask, marginal, out + (size_t)NTOK * NG * NDCV);
}